// Round 7
// baseline (312.927 us; speedup 1.0000x reference)
//
#include <hip/hip_runtime.h>
#include <hip/hip_bf16.h>

#define D_MODEL 768
#define N_HEADS 12
#define D_K     64
#define NEG_INF (-1e9f)
#define SCALE_Q 0.1803368801111154f  // 0.125 * log2(e): exp2-domain softmax
#define W_ELEMS (D_MODEL * D_MODEL)

typedef __attribute__((ext_vector_type(8))) short          bf16x8;
typedef __attribute__((ext_vector_type(4))) float          floatx4;
typedef __attribute__((ext_vector_type(4))) unsigned short ushortx4;
typedef __attribute__((ext_vector_type(2))) unsigned int   uintx2;
typedef __attribute__((ext_vector_type(4))) unsigned int   uintx4;

static __device__ __forceinline__ unsigned short f2bf(float f) {
    unsigned u = __builtin_bit_cast(unsigned, f);
    u += 0x7FFFu + ((u >> 16) & 1u);
    return (unsigned short)(u >> 16);
}

// async 16B/lane global->LDS (lds dest = wave-uniform base + lane*16)
static __device__ __forceinline__ void gload_lds16(const void* g, void* l) {
    __builtin_amdgcn_global_load_lds(
        (const __attribute__((address_space(1))) void*)g,
        (__attribute__((address_space(3))) void*)l, 16, 0, 0);
}

// ---------------------------------------------------------------------------
// fp32 -> bf16 converters.
// ---------------------------------------------------------------------------
__global__ __launch_bounds__(256) void convert_w4(
    const float* __restrict__ W0, const float* __restrict__ W1,
    const float* __restrict__ W2, const float* __restrict__ W3,
    unsigned short* __restrict__ out)
{
    const float* src[4] = {W0, W1, W2, W3};
    const float* W = src[blockIdx.y];
    unsigned short* o = out + (size_t)blockIdx.y * W_ELEMS;
    const int i = (blockIdx.x * 256 + threadIdx.x) * 4;
    float4 v = *(const float4*)(W + i);
    ushortx4 h = { f2bf(v.x), f2bf(v.y), f2bf(v.z), f2bf(v.w) };
    *(ushortx4*)(o + i) = h;
}

__global__ __launch_bounds__(256) void convert_a3(
    const float* __restrict__ A0, const float* __restrict__ A1,
    const float* __restrict__ A2,
    unsigned short* __restrict__ O0, unsigned short* __restrict__ O1,
    unsigned short* __restrict__ O2)
{
    const int z = blockIdx.y;
    const float* A = (z == 0) ? A0 : (z == 1) ? A1 : A2;
    unsigned short* O = (z == 0) ? O0 : (z == 1) ? O1 : O2;
    const int i = (blockIdx.x * 256 + threadIdx.x) * 4;
    float4 v = *(const float4*)(A + i);
    ushortx4 h = { f2bf(v.x), f2bf(v.y), f2bf(v.z), f2bf(v.w) };
    *(ushortx4*)(O + i) = h;
}

// ---------------------------------------------------------------------------
// C[M,N] = A[M,K] @ W[N,K]^T + bias[N];  A, W bf16; K = N = 768.
// m97 shape: 128x128 block tile, BK=32, 4 waves in 2x2 (64x64/wave),
// acc[4][4] -> 32 MFMA per barrier pair. Async global_load_lds staging.
// MFMA operand-swapped: D rows (quad*4+r) = n, cols (l16) = m -> vectorized
// stores along n. QKV: grid.z selects {Q(scale,bf16), K(bf16), V(->VpT)}.
// !QKV: single fp32 output (the final O @ Wo^T).
// ---------------------------------------------------------------------------
template <bool QKV>
__global__ __launch_bounds__(256) void gemm128(
    const unsigned short* __restrict__ A0, const unsigned short* __restrict__ A1,
    const unsigned short* __restrict__ A2,
    const unsigned short* __restrict__ W0, const unsigned short* __restrict__ W1,
    const unsigned short* __restrict__ W2,
    const float* __restrict__ b0, const float* __restrict__ b1,
    const float* __restrict__ b2,
    void* __restrict__ C0, void* __restrict__ C1, void* __restrict__ C2,
    int S)
{
    __shared__ __align__(16) unsigned short As[128 * 32];
    __shared__ __align__(16) unsigned short Bs[128 * 32];

    const int z = QKV ? blockIdx.z : 0;
    const unsigned short* A = (z == 0) ? A0 : (z == 1) ? A1 : A2;
    const unsigned short* W = (z == 0) ? W0 : (z == 1) ? W1 : W2;
    const float* bias       = (z == 0) ? b0 : (z == 1) ? b1 : b2;
    void* C                 = (z == 0) ? C0 : (z == 1) ? C1 : C2;
    const float scale = (QKV && z == 0) ? SCALE_Q : 1.0f;
    const int mode = QKV ? ((z == 2) ? 3 : 1) : 0;   // 3=VpT, 1=bf16, 0=fp32

    const int tid  = threadIdx.x;
    const int wave = tid >> 6;
    const int lane = tid & 63;
    const int quad = lane >> 4;
    const int l16  = lane & 15;
    const int m0 = blockIdx.x * 128;
    const int n0 = blockIdx.y * 128;
    const int wm = (wave & 1) * 64;
    const int wn = (wave >> 1) * 64;
    const int sr = lane >> 2;          // staging row within 16-row group
    const int sc = (lane & 3) << 3;    // staging col chunk (8 shorts = 16 B)

    const floatx4 zero4 = {0.f, 0.f, 0.f, 0.f};
    floatx4 acc[4][4];
    #pragma unroll
    for (int i = 0; i < 4; ++i)
        #pragma unroll
        for (int j = 0; j < 4; ++j) acc[i][j] = zero4;

    for (int k0 = 0; k0 < D_MODEL; k0 += 32) {
        // wave stages A rows [32w,32w+32) and W rows [32w,32w+32), 16/call
        #pragma unroll
        for (int c = 0; c < 2; ++c) {
            const int row = wave * 32 + c * 16;
            gload_lds16(A + (size_t)(m0 + row + sr) * D_MODEL + k0 + sc,
                        As + row * 32);
            gload_lds16(W + (size_t)(n0 + row + sr) * D_MODEL + k0 + sc,
                        Bs + row * 32);
        }
        __syncthreads();

        bf16x8 af[4], bfr[4];
        #pragma unroll
        for (int i = 0; i < 4; ++i)
            af[i] = *(const bf16x8*)(As + (wm + i * 16 + l16) * 32 + quad * 8);
        #pragma unroll
        for (int j = 0; j < 4; ++j)
            bfr[j] = *(const bf16x8*)(Bs + (wn + j * 16 + l16) * 32 + quad * 8);
        #pragma unroll
        for (int i = 0; i < 4; ++i)
            #pragma unroll
            for (int j = 0; j < 4; ++j)
                acc[i][j] = __builtin_amdgcn_mfma_f32_16x16x32_bf16(
                    bfr[j], af[i], acc[i][j], 0, 0, 0);   // swapped: rows=n
        __syncthreads();
    }

    // epilogue: D[i][j] rows (quad*4+r) = n, cols (l16) = m
    #pragma unroll
    for (int i = 0; i < 4; ++i) {
        const int m = m0 + wm + i * 16 + l16;
        #pragma unroll
        for (int j = 0; j < 4; ++j) {
            const int nb = n0 + wn + j * 16 + quad * 4;
            const float4 bv = *(const float4*)(bias + nb);
            float v0 = (acc[i][j][0] + bv.x) * scale;
            float v1 = (acc[i][j][1] + bv.y) * scale;
            float v2 = (acc[i][j][2] + bv.z) * scale;
            float v3 = (acc[i][j][3] + bv.w) * scale;
            if (mode == 0) {
                float4 o = {v0, v1, v2, v3};
                *(float4*)((float*)C + (size_t)m * D_MODEL + nb) = o;
            } else if (mode == 1) {
                ushortx4 o = {f2bf(v0), f2bf(v1), f2bf(v2), f2bf(v3)};
                *(ushortx4*)((unsigned short*)C + (size_t)m * D_MODEL + nb) = o;
            } else {
                // VpT[(bb*H + h)*64 + d][s]: 4 consecutive d, fixed s=m
                const int bb = m / S, s = m - bb * S;
                const int hh = nb >> 6, d = nb & 63;
                unsigned short* base = (unsigned short*)C +
                    ((size_t)(bb * N_HEADS + hh) * D_K + d) * S + s;
                base[0]         = f2bf(v0);
                base[(size_t)S]     = f2bf(v1);
                base[(size_t)S * 2] = f2bf(v2);
                base[(size_t)S * 3] = f2bf(v3);
            }
        }
    }
}

// ---------------------------------------------------------------------------
// Causal flash attention.
// R7 vs R6: KVBLK 128 -> 64 with DOUBLE-BUFFERED async-DMA staging (T3-lite,
// depth-1 prefetch). Per iteration: issue tile kt+1 DMAs into buf^1 at the
// TOP, compute QK^T/softmax/PV from buf, write-late the reg-prefetched mask,
// ONE barrier. The compiler's vmcnt(0)-before-barrier drain now waits on
// loads issued a full compute phase (~1000cy) earlier -- K/V are L2-resident
// (bh=L%24 XCD affinity, 3 (b,h) ~= 3MB/XCD < 4MB), so the wait is ~free.
// Same LDS total (33280B: Ks[2][64*64] + Vts[2][64*64] + mskf[2][64]),
// same barrier count (65 iters x 1 vs 33 x 2), same staged bytes.
// Load-balanced tile pairs (p, 63-p): (p+1)+(64-p) = 65 iters per block.
// XOR swizzle via pre-swizzled DMA source (m201/m173): conceptual (row,
// chunk p) holds global chunk p^(row&7); per-lane constant col (l&7)^(l>>3),
// row = wave*16 + c*8 + (l>>3). Reads XOR (l16&7)<<3 -> 2-way (free).
// P stays in registers (T12): PV A-operand via permlane32/16_swap.
// Row-sum via ones-MFMA, fixed-m exp2-domain softmax.
// ---------------------------------------------------------------------------
__global__ __launch_bounds__(256) void flash_attn(
    const unsigned short* __restrict__ Qp,
    const unsigned short* __restrict__ Kp,
    const unsigned short* __restrict__ VpT,
    const int* __restrict__ mask,
    unsigned short* __restrict__ O,   // bf16 [B*S, D_MODEL]
    int S)
{
    __shared__ __align__(16) unsigned short Ks [2][64 * 64];   // [key][d] swz
    __shared__ __align__(16) unsigned short Vts[2][64 * 64];   // [d][key] swz
    __shared__ __align__(16) float mskf[2][64];

    const int L  = blockIdx.x;
    const int bh = L % 24;
    const int p  = L / 24;
    const int h  = bh % 12;
    const int b  = bh / 12;
    const int nqt = S >> 6;
    const int tid  = threadIdx.x;
    const int wave = tid >> 6;
    const int lane = tid & 63;
    const int quad = lane >> 4;
    const int l16  = lane & 15;
    const int sx   = (l16 & 7) << 3;   // read-side swizzle field (shorts)

    const unsigned short* Kbase = Kp  + (size_t)(b * S) * D_MODEL + h * D_K;
    const unsigned short* Vbase = VpT + (size_t)(b * N_HEADS + h) * D_K * S;
    const int* mbase = mask + b * S;

    // DMA staging source map (per-lane constants): row = wave*16+c*8+(l>>3),
    // swizzled global col chunk = (l&7)^(l>>3)  [16B chunks]
    const int srow = wave * 16 + (lane >> 3);             // + c*8
    const int sgc  = ((lane & 7) ^ (lane >> 3)) << 3;     // shorts

    const floatx4 zero4 = {0.f, 0.f, 0.f, 0.f};
    const short one_bf = (short)0x3F80;  // bf16 1.0
    const bf16x8 ones = {one_bf, one_bf, one_bf, one_bf,
                         one_bf, one_bf, one_bf, one_bf};

    #pragma unroll
    for (int sel = 0; sel < 2; ++sel) {
        const int qt = sel ? (63 - p) : p;
        const int q0 = qt * 64;
        const int qbase = q0 + wave * 16;
        const int qabs = qbase + l16;       // this lane's q row (cols of S^T)

        // Q fragments (B-operand: n=l16, k=quad*8+j)
        const size_t rowQ = (size_t)(b * S + qbase + l16) * D_MODEL + h * D_K;
        const bf16x8 qf0 = *(const bf16x8*)(Qp + rowQ + quad * 8);
        const bf16x8 qf1 = *(const bf16x8*)(Qp + rowQ + 32 + quad * 8);

        floatx4 acc2[4];   // [d-tile]; C: col=d(l16), row=q(quad*4+r)
        floatx4 acc_l = zero4;
        #pragma unroll
        for (int dt = 0; dt < 4; ++dt) acc2[dt] = zero4;

        const int ni = qt + 1;   // 64-key iterations

        // prologue: stage tile 0 -> buf 0
        #pragma unroll
        for (int c = 0; c < 2; ++c) {
            gload_lds16(Kbase + (size_t)(srow + c * 8) * D_MODEL + sgc,
                        (char*)Ks[0] + (wave * 2 + c) * 1024);
            gload_lds16(Vbase + (size_t)(srow + c * 8) * S + sgc,
                        (char*)Vts[0] + (wave * 2 + c) * 1024);
        }
        if (tid < 64) mskf[0][tid] = (mbase[tid] == 0) ? NEG_INF : 0.f;
        __syncthreads();

        float mr = 0.f;
        for (int kt = 0; kt < ni; ++kt) {
            const int k0 = kt * 64;
            const int cur = kt & 1;
            const bool pre = (kt + 1 < ni);

            // issue tile kt+1 DMAs; latency hides under compute below
            if (pre) {
                const int kn = k0 + 64;
                #pragma unroll
                for (int c = 0; c < 2; ++c) {
                    gload_lds16(
                        Kbase + (size_t)(kn + srow + c * 8) * D_MODEL + sgc,
                        (char*)Ks[cur ^ 1] + (wave * 2 + c) * 1024);
                    gload_lds16(
                        Vbase + (size_t)(srow + c * 8) * S + kn + sgc,
                        (char*)Vts[cur ^ 1] + (wave * 2 + c) * 1024);
                }
                if (tid < 64) mr = (mbase[kn + tid] == 0) ? NEG_INF : 0.f;
            }

            // S^T = K Q^T + padding-mask-init: rows=keys(64), cols=q
            floatx4 s[4];
            #pragma unroll
            for (int nt = 0; nt < 4; ++nt) {
                floatx4 c = *(const floatx4*)(&mskf[cur][nt * 16 + quad * 4]);
                const unsigned short* kro = Ks[cur] + (nt * 16 + l16) * 64;
                bf16x8 kf0 = *(const bf16x8*)(kro + ((quad * 8) ^ sx));
                bf16x8 kf1 = *(const bf16x8*)(kro + ((32 + quad * 8) ^ sx));
                c = __builtin_amdgcn_mfma_f32_16x16x32_bf16(kf0, qf0, c, 0, 0, 0);
                c = __builtin_amdgcn_mfma_f32_16x16x32_bf16(kf1, qf1, c, 0, 0, 0);
                s[nt] = c;
            }

            // causal mask: only the last k-tile of this q-tile needs it
            if (kt == ni - 1) {
                #pragma unroll
                for (int nt = 0; nt < 4; ++nt) {
                    const int kb = k0 + nt * 16 + quad * 4;
                    #pragma unroll
                    for (int r = 0; r < 4; ++r)
                        if (kb + r > qabs) s[nt][r] = NEG_INF;
                }
            }

            // P = exp2(s), truncation-packed to bf16 pairs in registers:
            // pk0[nt] = keys (quad*4+0, +1), pk1[nt] = keys (quad*4+2, +3)
            unsigned pk0[4], pk1[4];
            #pragma unroll
            for (int nt = 0; nt < 4; ++nt) {
                const float e0 = __builtin_exp2f(s[nt][0]);
                const float e1 = __builtin_exp2f(s[nt][1]);
                const float e2 = __builtin_exp2f(s[nt][2]);
                const float e3 = __builtin_exp2f(s[nt][3]);
                pk0[nt] = __builtin_amdgcn_perm(__builtin_bit_cast(unsigned, e1),
                                                __builtin_bit_cast(unsigned, e0), 0x07060302u);
                pk1[nt] = __builtin_amdgcn_perm(__builtin_bit_cast(unsigned, e3),
                                                __builtin_bit_cast(unsigned, e2), 0x07060302u);
            }

            // O += P V ; l += P 1   (64 keys -> 2 kh steps)
            // A-operand built in-register: cross-quad redistribution at fixed
            // l16 via permlane32_swap + permlane16_swap (no LDS).
            #pragma unroll
            for (int kh = 0; kh < 2; ++kh) {
                uintx2 a32 = __builtin_amdgcn_permlane32_swap(
                    pk0[2 * kh], pk0[2 * kh + 1], false, false);
                uintx2 b32 = __builtin_amdgcn_permlane32_swap(
                    pk1[2 * kh], pk1[2 * kh + 1], false, false);
                uintx2 a16 = __builtin_amdgcn_permlane16_swap(
                    a32[0], a32[1], false, false);
                uintx2 b16 = __builtin_amdgcn_permlane16_swap(
                    b32[0], b32[1], false, false);
                const uintx4 pw = {a16[0], b16[0], a16[1], b16[1]};
                const bf16x8 pf = __builtin_bit_cast(bf16x8, pw);
                #pragma unroll
                for (int dt = 0; dt < 4; ++dt) {
                    const unsigned short* vro = Vts[cur] + (dt * 16 + l16) * 64;
                    bf16x8 vf = *(const bf16x8*)(vro + ((kh * 32 + quad * 8) ^ sx));
                    acc2[dt] = __builtin_amdgcn_mfma_f32_16x16x32_bf16(pf, vf, acc2[dt], 0, 0, 0);
                }
                acc_l = __builtin_amdgcn_mfma_f32_16x16x32_bf16(pf, ones, acc_l, 0, 0, 0);
            }

            // write-late: commit prefetched mask (load issued at top)
            if (pre && tid < 64) mskf[cur ^ 1][tid] = mr;
            __syncthreads();
        }

        // epilogue: O = acc / l
        #pragma unroll
        for (int r = 0; r < 4; ++r) {
            const float inv = 1.f / acc_l[r];
            const int gq = qbase + quad * 4 + r;
            const size_t base = (size_t)(b * S + gq) * D_MODEL + h * D_K;
            #pragma unroll
            for (int dt = 0; dt < 4; ++dt)
                O[base + dt * 16 + l16] = f2bf(acc2[dt][r] * inv);
        }
        // no extra barrier needed: next sel's prologue has its own barrier,
        // and buf contents were fully consumed before this point
    }
}

// ---------------------------------------------------------------------------
extern "C" void kernel_launch(void* const* d_in, const int* in_sizes, int n_in,
                              void* d_out, int out_size, void* d_ws, size_t ws_size,
                              hipStream_t stream) {
    const float* query = (const float*)d_in[0];
    const float* key   = (const float*)d_in[1];
    const float* value = (const float*)d_in[2];
    const int*   mask  = (const int*)d_in[3];
    const float* Wq = (const float*)d_in[4];
    const float* bq = (const float*)d_in[5];
    const float* Wk = (const float*)d_in[6];
    const float* bk = (const float*)d_in[7];
    const float* Wv = (const float*)d_in[8];
    const float* bv = (const float*)d_in[9];
    const float* Wo = (const float*)d_in[10];
    const float* bo = (const float*)d_in[11];

    const int B  = 2;
    const int BS = in_sizes[3];
    const int S  = BS / B;
    const int M  = BS;

    unsigned short* Qp  = (unsigned short*)d_ws;
    unsigned short* Kp  = Qp  + (size_t)M * D_MODEL;
    unsigned short* VpT = Kp  + (size_t)M * D_MODEL;
    unsigned short* Obf = VpT + (size_t)M * D_MODEL;  // qa staging, then O
    unsigned short* Wbf = Obf + (size_t)M * D_MODEL;
    unsigned short* Wqb = Wbf;
    unsigned short* Wkb = Wbf + (size_t)W_ELEMS;
    unsigned short* Wvb = Wbf + (size_t)W_ELEMS * 2;
    unsigned short* Wob = Wbf + (size_t)W_ELEMS * 3;
    // d_out (25.2 MB fp32) doubles as scratch for ka/va bf16 until final GEMM
    unsigned short* ka = (unsigned short*)d_out;
    unsigned short* va = ka + (size_t)M * D_MODEL;

    dim3 blk(256);
    convert_w4<<<dim3(W_ELEMS / 1024, 4), blk, 0, stream>>>(Wq, Wk, Wv, Wo, Wbf);
    convert_a3<<<dim3((M * D_MODEL) / 1024, 3), blk, 0, stream>>>(
        query, key, value, Obf, ka, va);

    gemm128<true><<<dim3(M / 128, D_MODEL / 128, 3), blk, 0, stream>>>(
        Obf, ka, va, Wqb, Wkb, Wvb, bq, bk, bv, Qp, Kp, VpT, S);

    flash_attn<<<768, blk, 0, stream>>>(Qp, Kp, VpT, mask, Obf, S);

    gemm128<false><<<dim3(M / 128, D_MODEL / 128, 1), blk, 0, stream>>>(
        Obf, Obf, Obf, Wob, Wob, Wob, bo, bo, bo,
        d_out, d_out, d_out, S);
}

// Round 8
// 305.225 us; speedup vs baseline: 1.0252x; 1.0252x over previous
//
#include <hip/hip_runtime.h>
#include <hip/hip_bf16.h>

#define D_MODEL 768
#define N_HEADS 12
#define D_K     64
#define NEG_INF (-1e9f)
#define SCALE_Q 0.1803368801111154f  // 0.125 * log2(e): exp2-domain softmax
#define W_ELEMS (D_MODEL * D_MODEL)

typedef __attribute__((ext_vector_type(8))) short          bf16x8;
typedef __attribute__((ext_vector_type(4))) float          floatx4;
typedef __attribute__((ext_vector_type(4))) unsigned short ushortx4;
typedef __attribute__((ext_vector_type(2))) unsigned int   uintx2;
typedef __attribute__((ext_vector_type(4))) unsigned int   uintx4;

static __device__ __forceinline__ unsigned short f2bf(float f) {
    unsigned u = __builtin_bit_cast(unsigned, f);
    u += 0x7FFFu + ((u >> 16) & 1u);
    return (unsigned short)(u >> 16);
}

// async 16B/lane global->LDS (lds dest = wave-uniform base + lane*16)
static __device__ __forceinline__ void gload_lds16(const void* g, void* l) {
    __builtin_amdgcn_global_load_lds(
        (const __attribute__((address_space(1))) void*)g,
        (__attribute__((address_space(3))) void*)l, 16, 0, 0);
}

// ---------------------------------------------------------------------------
// fp32 -> bf16 converters.
// ---------------------------------------------------------------------------
__global__ __launch_bounds__(256) void convert_w4(
    const float* __restrict__ W0, const float* __restrict__ W1,
    const float* __restrict__ W2, const float* __restrict__ W3,
    unsigned short* __restrict__ out)
{
    const float* src[4] = {W0, W1, W2, W3};
    const float* W = src[blockIdx.y];
    unsigned short* o = out + (size_t)blockIdx.y * W_ELEMS;
    const int i = (blockIdx.x * 256 + threadIdx.x) * 4;
    float4 v = *(const float4*)(W + i);
    ushortx4 h = { f2bf(v.x), f2bf(v.y), f2bf(v.z), f2bf(v.w) };
    *(ushortx4*)(o + i) = h;
}

__global__ __launch_bounds__(256) void convert_a3(
    const float* __restrict__ A0, const float* __restrict__ A1,
    const float* __restrict__ A2,
    unsigned short* __restrict__ O0, unsigned short* __restrict__ O1,
    unsigned short* __restrict__ O2)
{
    const int z = blockIdx.y;
    const float* A = (z == 0) ? A0 : (z == 1) ? A1 : A2;
    unsigned short* O = (z == 0) ? O0 : (z == 1) ? O1 : O2;
    const int i = (blockIdx.x * 256 + threadIdx.x) * 4;
    float4 v = *(const float4*)(A + i);
    ushortx4 h = { f2bf(v.x), f2bf(v.y), f2bf(v.z), f2bf(v.w) };
    *(ushortx4*)(O + i) = h;
}

// ---------------------------------------------------------------------------
// C[M,N] = A[M,K] @ W[N,K]^T + bias[N];  A, W bf16; K = N = 768.
// m97 shape: 128x128 block tile, BK=32, 4 waves in 2x2 (64x64/wave),
// acc[4][4] -> 32 MFMA per barrier pair. Async global_load_lds staging.
// MFMA operand-swapped: D rows (quad*4+r) = n, cols (l16) = m -> vectorized
// stores along n. QKV only: grid.z selects {Q(scale,bf16), K(bf16), V(->VpT)}.
// ---------------------------------------------------------------------------
__global__ __launch_bounds__(256) void gemm128(
    const unsigned short* __restrict__ A0, const unsigned short* __restrict__ A1,
    const unsigned short* __restrict__ A2,
    const unsigned short* __restrict__ W0, const unsigned short* __restrict__ W1,
    const unsigned short* __restrict__ W2,
    const float* __restrict__ b0, const float* __restrict__ b1,
    const float* __restrict__ b2,
    void* __restrict__ C0, void* __restrict__ C1, void* __restrict__ C2,
    int S)
{
    __shared__ __align__(16) unsigned short As[128 * 32];
    __shared__ __align__(16) unsigned short Bs[128 * 32];

    const int z = blockIdx.z;
    const unsigned short* A = (z == 0) ? A0 : (z == 1) ? A1 : A2;
    const unsigned short* W = (z == 0) ? W0 : (z == 1) ? W1 : W2;
    const float* bias       = (z == 0) ? b0 : (z == 1) ? b1 : b2;
    void* C                 = (z == 0) ? C0 : (z == 1) ? C1 : C2;
    const float scale = (z == 0) ? SCALE_Q : 1.0f;
    const int mode = (z == 2) ? 3 : 1;   // 3=VpT, 1=bf16

    const int tid  = threadIdx.x;
    const int wave = tid >> 6;
    const int lane = tid & 63;
    const int quad = lane >> 4;
    const int l16  = lane & 15;
    const int m0 = blockIdx.x * 128;
    const int n0 = blockIdx.y * 128;
    const int wm = (wave & 1) * 64;
    const int wn = (wave >> 1) * 64;
    const int sr = lane >> 2;          // staging row within 16-row group
    const int sc = (lane & 3) << 3;    // staging col chunk (8 shorts = 16 B)

    const floatx4 zero4 = {0.f, 0.f, 0.f, 0.f};
    floatx4 acc[4][4];
    #pragma unroll
    for (int i = 0; i < 4; ++i)
        #pragma unroll
        for (int j = 0; j < 4; ++j) acc[i][j] = zero4;

    for (int k0 = 0; k0 < D_MODEL; k0 += 32) {
        // wave stages A rows [32w,32w+32) and W rows [32w,32w+32), 16/call
        #pragma unroll
        for (int c = 0; c < 2; ++c) {
            const int row = wave * 32 + c * 16;
            gload_lds16(A + (size_t)(m0 + row + sr) * D_MODEL + k0 + sc,
                        As + row * 32);
            gload_lds16(W + (size_t)(n0 + row + sr) * D_MODEL + k0 + sc,
                        Bs + row * 32);
        }
        __syncthreads();

        bf16x8 af[4], bfr[4];
        #pragma unroll
        for (int i = 0; i < 4; ++i)
            af[i] = *(const bf16x8*)(As + (wm + i * 16 + l16) * 32 + quad * 8);
        #pragma unroll
        for (int j = 0; j < 4; ++j)
            bfr[j] = *(const bf16x8*)(Bs + (wn + j * 16 + l16) * 32 + quad * 8);
        #pragma unroll
        for (int i = 0; i < 4; ++i)
            #pragma unroll
            for (int j = 0; j < 4; ++j)
                acc[i][j] = __builtin_amdgcn_mfma_f32_16x16x32_bf16(
                    bfr[j], af[i], acc[i][j], 0, 0, 0);   // swapped: rows=n
        __syncthreads();
    }

    // epilogue: D[i][j] rows (quad*4+r) = n, cols (l16) = m
    #pragma unroll
    for (int i = 0; i < 4; ++i) {
        const int m = m0 + wm + i * 16 + l16;
        #pragma unroll
        for (int j = 0; j < 4; ++j) {
            const int nb = n0 + wn + j * 16 + quad * 4;
            const float4 bv = *(const float4*)(bias + nb);
            float v0 = (acc[i][j][0] + bv.x) * scale;
            float v1 = (acc[i][j][1] + bv.y) * scale;
            float v2 = (acc[i][j][2] + bv.z) * scale;
            float v3 = (acc[i][j][3] + bv.w) * scale;
            if (mode == 1) {
                ushortx4 o = {f2bf(v0), f2bf(v1), f2bf(v2), f2bf(v3)};
                *(ushortx4*)((unsigned short*)C + (size_t)m * D_MODEL + nb) = o;
            } else {
                // VpT[(bb*H + h)*64 + d][s]: 4 consecutive d, fixed s=m
                const int bb = m / S, s = m - bb * S;
                const int hh = nb >> 6, d = nb & 63;
                unsigned short* base = (unsigned short*)C +
                    ((size_t)(bb * N_HEADS + hh) * D_K + d) * S + s;
                base[0]         = f2bf(v0);
                base[(size_t)S]     = f2bf(v1);
                base[(size_t)S * 2] = f2bf(v2);
                base[(size_t)S * 3] = f2bf(v3);
            }
        }
    }
}

// ---------------------------------------------------------------------------
// Final O @ Wo^T + bo -> fp32. R8: 64x128 output tile -> grid (M/64, 6) =
// 768 blocks = EXACTLY 3 blocks/CU (12 waves/CU, the m97 occupancy point).
// The previous 128x128 tiling launched only 384 blocks (1.5/CU): half the
// CUs ran one 4-wave block (1 wave/SIMD) -- latency-crippled. 4 waves side
// by side in N: wave owns 64x32, acc[4][2], 8 MFMA/k-iter. Staging: 12
// gload_lds16 calls (As 4 groups of 16 rows, Bs 8) = 3 calls/wave.
// ---------------------------------------------------------------------------
__global__ __launch_bounds__(256) void gemm64o(
    const unsigned short* __restrict__ A,
    const unsigned short* __restrict__ W,
    const float* __restrict__ bias,
    float* __restrict__ C)
{
    __shared__ __align__(16) unsigned short As[64 * 32];
    __shared__ __align__(16) unsigned short Bs[128 * 32];

    const int tid  = threadIdx.x;
    const int wave = tid >> 6;
    const int lane = tid & 63;
    const int quad = lane >> 4;
    const int l16  = lane & 15;
    const int m0 = blockIdx.x * 64;
    const int n0 = blockIdx.y * 128;
    const int wn = wave * 32;
    const int sr = lane >> 2;          // staging row within 16-row group
    const int sc = (lane & 3) << 3;    // staging col chunk (8 shorts = 16 B)

    const floatx4 zero4 = {0.f, 0.f, 0.f, 0.f};
    floatx4 acc[4][2];
    #pragma unroll
    for (int i = 0; i < 4; ++i)
        #pragma unroll
        for (int j = 0; j < 2; ++j) acc[i][j] = zero4;

    for (int k0 = 0; k0 < D_MODEL; k0 += 32) {
        // staging: waves 0,1 -> As rows [32w,32w+32) + Bs group 96/112;
        //          waves 2,3 -> Bs rows [48(w-2), 48(w-2)+48)
        if (wave < 2) {
            const int g0 = wave * 32;
            gload_lds16(A + (size_t)(m0 + g0 + sr) * D_MODEL + k0 + sc,
                        As + g0 * 32);
            gload_lds16(A + (size_t)(m0 + g0 + 16 + sr) * D_MODEL + k0 + sc,
                        As + (g0 + 16) * 32);
            const int bg = 96 + wave * 16;
            gload_lds16(W + (size_t)(n0 + bg + sr) * D_MODEL + k0 + sc,
                        Bs + bg * 32);
        } else {
            const int bg = (wave - 2) * 48;
            #pragma unroll
            for (int c = 0; c < 3; ++c)
                gload_lds16(W + (size_t)(n0 + bg + c * 16 + sr) * D_MODEL + k0 + sc,
                            Bs + (bg + c * 16) * 32);
        }
        __syncthreads();

        bf16x8 af[4], bfr[2];
        #pragma unroll
        for (int i = 0; i < 4; ++i)
            af[i] = *(const bf16x8*)(As + (i * 16 + l16) * 32 + quad * 8);
        #pragma unroll
        for (int j = 0; j < 2; ++j)
            bfr[j] = *(const bf16x8*)(Bs + (wn + j * 16 + l16) * 32 + quad * 8);
        #pragma unroll
        for (int i = 0; i < 4; ++i)
            #pragma unroll
            for (int j = 0; j < 2; ++j)
                acc[i][j] = __builtin_amdgcn_mfma_f32_16x16x32_bf16(
                    bfr[j], af[i], acc[i][j], 0, 0, 0);   // swapped: rows=n
        __syncthreads();
    }

    // epilogue: D[i][j] rows (quad*4+r) = n, cols (l16) = m
    #pragma unroll
    for (int i = 0; i < 4; ++i) {
        const int m = m0 + i * 16 + l16;
        #pragma unroll
        for (int j = 0; j < 2; ++j) {
            const int nb = n0 + wn + j * 16 + quad * 4;
            const float4 bv = *(const float4*)(bias + nb);
            float4 o = {acc[i][j][0] + bv.x, acc[i][j][1] + bv.y,
                        acc[i][j][2] + bv.z, acc[i][j][3] + bv.w};
            *(float4*)(C + (size_t)m * D_MODEL + nb) = o;
        }
    }
}

// ---------------------------------------------------------------------------
// Causal flash attention: 128-key k-iterations, load-balanced tile pairs
// (p, 63-p) -> every block runs exactly 33 k-iterations (grid 768 = 3
// blocks/CU). XCD swizzle: bh = L%24 keeps each (b,h)'s 32 blocks on one
// XCD's L2. Operand-swapped QK^T (rows=keys, cols=q), P-in-registers via
// permlane32/16_swap (T12), row-sum via ones-MFMA, fixed-m exp2 softmax.
// R6 staging (best measured): K/V via async global_load_lds (width 16),
// bank-conflict fix by PRE-SWIZZLING the per-lane global source address
// (m201/m173; XOR involution -> source-permute == read-permute):
//   conceptual (row, chunk p) holds global chunk p ^ (row&7)   [16B chunks]
// K[128][64]: lane l call c stages row w*32+c*8+(l>>3), global chunk
// (l&7)^(l>>3) -- per-lane constant. V[64][128]: row w*16+c*4+(l>>4),
// global chunk (l&15)^((c&1)*4+(l>>4)). Reads XOR (row&7)<<3 -> 2-way (free).
// ---------------------------------------------------------------------------
__global__ __launch_bounds__(256) void flash_attn(
    const unsigned short* __restrict__ Qp,
    const unsigned short* __restrict__ Kp,
    const unsigned short* __restrict__ VpT,
    const int* __restrict__ mask,
    unsigned short* __restrict__ O,   // bf16 [B*S, D_MODEL]
    int S)
{
    __shared__ __align__(16) unsigned short Ks [128 * 64];   // [key][d]  swz
    __shared__ __align__(16) unsigned short Vts[64 * 128];   // [d][key]  swz
    __shared__ __align__(16) float mskf[128];

    const int L  = blockIdx.x;
    const int bh = L % 24;
    const int p  = L / 24;
    const int h  = bh % 12;
    const int b  = bh / 12;
    const int nqt = S >> 6;
    const int tid  = threadIdx.x;
    const int wave = tid >> 6;
    const int lane = tid & 63;
    const int quad = lane >> 4;
    const int l16  = lane & 15;
    const int sx   = (l16 & 7) << 3;   // read-side swizzle field (shorts)

    const unsigned short* Kbase = Kp  + (size_t)(b * S) * D_MODEL + h * D_K;
    const unsigned short* Vbase = VpT + (size_t)(b * N_HEADS + h) * D_K * S;
    const int* mbase = mask + b * S;

    // DMA staging source maps (per-lane constants)
    const int kgrow = wave * 32 + (lane >> 3);            // + c*8
    const int kgcol = ((lane & 7) ^ (lane >> 3)) << 3;
    const int vgrow = wave * 16 + (lane >> 4);            // + c*4
    const int vgc_e = ((lane & 15) ^ (lane >> 4)) << 3;        // even c
    const int vgc_o = ((lane & 15) ^ (4 + (lane >> 4))) << 3;  // odd  c

    const floatx4 zero4 = {0.f, 0.f, 0.f, 0.f};
    const short one_bf = (short)0x3F80;  // bf16 1.0
    const bf16x8 ones = {one_bf, one_bf, one_bf, one_bf,
                         one_bf, one_bf, one_bf, one_bf};

    #pragma unroll
    for (int sel = 0; sel < 2; ++sel) {
        const int qt = sel ? (nqt - 1 - p) : p;
        const int q0 = qt * 64;
        const int qbase = q0 + wave * 16;
        const int qabs = qbase + l16;       // this lane's q row (cols of S^T)

        // Q fragments (B-operand: n=l16, k=quad*8+j)
        const size_t rowQ = (size_t)(b * S + qbase + l16) * D_MODEL + h * D_K;
        const bf16x8 qf0 = *(const bf16x8*)(Qp + rowQ + quad * 8);
        const bf16x8 qf1 = *(const bf16x8*)(Qp + rowQ + 32 + quad * 8);

        floatx4 acc2[4];   // [d-tile]; C: col=d(l16), row=q(quad*4+r)
        floatx4 acc_l = zero4;
        #pragma unroll
        for (int dt = 0; dt < 4; ++dt) acc2[dt] = zero4;

        const int ni = (qt >> 1) + 1;
        for (int kt = 0; kt < ni; ++kt) {
            const int k0 = kt * 128;
            // stage K [128 keys][64 d] and V^T [64 d][128 keys] via async
            // DMA, source pre-swizzled (see header comment)
            #pragma unroll
            for (int c = 0; c < 4; ++c) {
                gload_lds16(
                    Kbase + (size_t)(k0 + kgrow + c * 8) * D_MODEL + kgcol,
                    (char*)Ks + (wave * 4 + c) * 1024);
                const int vg = (c & 1) ? vgc_o : vgc_e;
                gload_lds16(
                    Vbase + (size_t)(vgrow + c * 4) * S + k0 + vg,
                    (char*)Vts + (wave * 4 + c) * 1024);
            }
            if (tid < 128)
                mskf[tid] = (mbase[k0 + tid] == 0) ? NEG_INF : 0.f;
            __syncthreads();

            // S^T = K Q^T + padding-mask-init: rows=keys, cols=q
            floatx4 s[8];
            #pragma unroll
            for (int nt = 0; nt < 8; ++nt) {
                floatx4 c = *(const floatx4*)(mskf + nt * 16 + quad * 4);
                const unsigned short* kro = Ks + (nt * 16 + l16) * 64;
                bf16x8 kf0 = *(const bf16x8*)(kro + ((quad * 8) ^ sx));
                bf16x8 kf1 = *(const bf16x8*)(kro + ((32 + quad * 8) ^ sx));
                c = __builtin_amdgcn_mfma_f32_16x16x32_bf16(kf0, qf0, c, 0, 0, 0);
                c = __builtin_amdgcn_mfma_f32_16x16x32_bf16(kf1, qf1, c, 0, 0, 0);
                s[nt] = c;
            }

            // causal mask: only the last k-tile of this q-tile needs it
            if (kt == ni - 1) {
                #pragma unroll
                for (int nt = 0; nt < 8; ++nt) {
                    const int kb = k0 + nt * 16 + quad * 4;
                    #pragma unroll
                    for (int r = 0; r < 4; ++r)
                        if (kb + r > qabs) s[nt][r] = NEG_INF;
                }
            }

            // P = exp2(s), truncation-packed to bf16 pairs in registers:
            // pk0[nt] = keys (quad*4+0, +1), pk1[nt] = keys (quad*4+2, +3)
            unsigned pk0[8], pk1[8];
            #pragma unroll
            for (int nt = 0; nt < 8; ++nt) {
                const float e0 = __builtin_exp2f(s[nt][0]);
                const float e1 = __builtin_exp2f(s[nt][1]);
                const float e2 = __builtin_exp2f(s[nt][2]);
                const float e3 = __builtin_exp2f(s[nt][3]);
                pk0[nt] = __builtin_amdgcn_perm(__builtin_bit_cast(unsigned, e1),
                                                __builtin_bit_cast(unsigned, e0), 0x07060302u);
                pk1[nt] = __builtin_amdgcn_perm(__builtin_bit_cast(unsigned, e3),
                                                __builtin_bit_cast(unsigned, e2), 0x07060302u);
            }

            // O += P V ; l += P 1   (K=128 keys -> 4 kh steps)
            // A-operand built in-register: cross-quad redistribution at fixed
            // l16 via permlane32_swap + permlane16_swap (no LDS).
            #pragma unroll
            for (int kh = 0; kh < 4; ++kh) {
                uintx2 a32 = __builtin_amdgcn_permlane32_swap(
                    pk0[2 * kh], pk0[2 * kh + 1], false, false);
                uintx2 b32 = __builtin_amdgcn_permlane32_swap(
                    pk1[2 * kh], pk1[2 * kh + 1], false, false);
                uintx2 a16 = __builtin_amdgcn_permlane16_swap(
                    a32[0], a32[1], false, false);
                uintx2 b16 = __builtin_amdgcn_permlane16_swap(
                    b32[0], b32[1], false, false);
                const uintx4 pw = {a16[0], b16[0], a16[1], b16[1]};
                const bf16x8 pf = __builtin_bit_cast(bf16x8, pw);
                #pragma unroll
                for (int dt = 0; dt < 4; ++dt) {
                    const unsigned short* vro = Vts + (dt * 16 + l16) * 128;
                    bf16x8 vf = *(const bf16x8*)(vro + ((kh * 32 + quad * 8) ^ sx));
                    acc2[dt] = __builtin_amdgcn_mfma_f32_16x16x32_bf16(pf, vf, acc2[dt], 0, 0, 0);
                }
                acc_l = __builtin_amdgcn_mfma_f32_16x16x32_bf16(pf, ones, acc_l, 0, 0, 0);
            }
            __syncthreads();
        }

        // epilogue: O = acc / l
        #pragma unroll
        for (int r = 0; r < 4; ++r) {
            const float inv = 1.f / acc_l[r];
            const int gq = qbase + quad * 4 + r;
            const size_t base = (size_t)(b * S + gq) * D_MODEL + h * D_K;
            #pragma unroll
            for (int dt = 0; dt < 4; ++dt)
                O[base + dt * 16 + l16] = f2bf(acc2[dt][r] * inv);
        }
        __syncthreads();  // LDS reused by second tile
    }
}

// ---------------------------------------------------------------------------
extern "C" void kernel_launch(void* const* d_in, const int* in_sizes, int n_in,
                              void* d_out, int out_size, void* d_ws, size_t ws_size,
                              hipStream_t stream) {
    const float* query = (const float*)d_in[0];
    const float* key   = (const float*)d_in[1];
    const float* value = (const float*)d_in[2];
    const int*   mask  = (const int*)d_in[3];
    const float* Wq = (const float*)d_in[4];
    const float* bq = (const float*)d_in[5];
    const float* Wk = (const float*)d_in[6];
    const float* bk = (const float*)d_in[7];
    const float* Wv = (const float*)d_in[8];
    const float* bv = (const float*)d_in[9];
    const float* Wo = (const float*)d_in[10];
    const float* bo = (const float*)d_in[11];

    const int B  = 2;
    const int BS = in_sizes[3];
    const int S  = BS / B;
    const int M  = BS;

    unsigned short* Qp  = (unsigned short*)d_ws;
    unsigned short* Kp  = Qp  + (size_t)M * D_MODEL;
    unsigned short* VpT = Kp  + (size_t)M * D_MODEL;
    unsigned short* Obf = VpT + (size_t)M * D_MODEL;  // qa staging, then O
    unsigned short* Wbf = Obf + (size_t)M * D_MODEL;
    unsigned short* Wqb = Wbf;
    unsigned short* Wkb = Wbf + (size_t)W_ELEMS;
    unsigned short* Wvb = Wbf + (size_t)W_ELEMS * 2;
    unsigned short* Wob = Wbf + (size_t)W_ELEMS * 3;
    // d_out (25.2 MB fp32) doubles as scratch for ka/va bf16 until final GEMM
    unsigned short* ka = (unsigned short*)d_out;
    unsigned short* va = ka + (size_t)M * D_MODEL;

    dim3 blk(256);
    convert_w4<<<dim3(W_ELEMS / 1024, 4), blk, 0, stream>>>(Wq, Wk, Wv, Wo, Wbf);
    convert_a3<<<dim3((M * D_MODEL) / 1024, 3), blk, 0, stream>>>(
        query, key, value, Obf, ka, va);

    gemm128<<<dim3(M / 128, D_MODEL / 128, 3), blk, 0, stream>>>(
        Obf, ka, va, Wqb, Wkb, Wvb, bq, bk, bv, Qp, Kp, VpT, S);

    flash_attn<<<768, blk, 0, stream>>>(Qp, Kp, VpT, mask, Obf, S);

    gemm64o<<<dim3(M / 64, D_MODEL / 128), blk, 0, stream>>>(
        Obf, Wob, bo, (float*)d_out);
}

// Round 9
// 295.007 us; speedup vs baseline: 1.0607x; 1.0346x over previous
//
#include <hip/hip_runtime.h>
#include <hip/hip_bf16.h>

#define D_MODEL 768
#define N_HEADS 12
#define D_K     64
#define NEG_INF (-1e9f)
#define SCALE_Q 0.1803368801111154f  // 0.125 * log2(e): exp2-domain softmax
#define W_ELEMS (D_MODEL * D_MODEL)

typedef __attribute__((ext_vector_type(8))) short          bf16x8;
typedef __attribute__((ext_vector_type(4))) float          floatx4;
typedef __attribute__((ext_vector_type(4))) unsigned short ushortx4;
typedef __attribute__((ext_vector_type(2))) unsigned int   uintx2;
typedef __attribute__((ext_vector_type(4))) unsigned int   uintx4;

static __device__ __forceinline__ unsigned short f2bf(float f) {
    unsigned u = __builtin_bit_cast(unsigned, f);
    u += 0x7FFFu + ((u >> 16) & 1u);
    return (unsigned short)(u >> 16);
}

// raw v_exp_f32 (2^x): skips ocml's denormal-guard sequence (~5 VALU/call).
// Domain here: s in [-1.8e8, ~+40] -> flush-to-zero on tiny results is fine.
static __device__ __forceinline__ float exp2_hw(float x) {
#if __has_builtin(__builtin_amdgcn_exp2f)
    return __builtin_amdgcn_exp2f(x);
#else
    return __builtin_exp2f(x);
#endif
}

static __device__ __forceinline__ float rcp_hw(float x) {
#if __has_builtin(__builtin_amdgcn_rcpf)
    return __builtin_amdgcn_rcpf(x);
#else
    return 1.f / x;
#endif
}

// async 16B/lane global->LDS (lds dest = wave-uniform base + lane*16)
static __device__ __forceinline__ void gload_lds16(const void* g, void* l) {
    __builtin_amdgcn_global_load_lds(
        (const __attribute__((address_space(1))) void*)g,
        (__attribute__((address_space(3))) void*)l, 16, 0, 0);
}

// ---------------------------------------------------------------------------
// fp32 -> bf16 converters.
// ---------------------------------------------------------------------------
__global__ __launch_bounds__(256) void convert_w4(
    const float* __restrict__ W0, const float* __restrict__ W1,
    const float* __restrict__ W2, const float* __restrict__ W3,
    unsigned short* __restrict__ out)
{
    const float* src[4] = {W0, W1, W2, W3};
    const float* W = src[blockIdx.y];
    unsigned short* o = out + (size_t)blockIdx.y * W_ELEMS;
    const int i = (blockIdx.x * 256 + threadIdx.x) * 4;
    float4 v = *(const float4*)(W + i);
    ushortx4 h = { f2bf(v.x), f2bf(v.y), f2bf(v.z), f2bf(v.w) };
    *(ushortx4*)(o + i) = h;
}

__global__ __launch_bounds__(256) void convert_a3(
    const float* __restrict__ A0, const float* __restrict__ A1,
    const float* __restrict__ A2,
    unsigned short* __restrict__ O0, unsigned short* __restrict__ O1,
    unsigned short* __restrict__ O2)
{
    const int z = blockIdx.y;
    const float* A = (z == 0) ? A0 : (z == 1) ? A1 : A2;
    unsigned short* O = (z == 0) ? O0 : (z == 1) ? O1 : O2;
    const int i = (blockIdx.x * 256 + threadIdx.x) * 4;
    float4 v = *(const float4*)(A + i);
    ushortx4 h = { f2bf(v.x), f2bf(v.y), f2bf(v.z), f2bf(v.w) };
    *(ushortx4*)(O + i) = h;
}

// ---------------------------------------------------------------------------
// C[M,N] = A[M,K] @ W[N,K]^T + bias[N];  A, W bf16; K = N = 768.
// m97 shape: 128x128 block tile, BK=32, 4 waves in 2x2 (64x64/wave),
// acc[4][4] -> 32 MFMA per barrier pair. Async global_load_lds staging.
// MFMA operand-swapped: D rows (quad*4+r) = n, cols (l16) = m -> vectorized
// stores along n. QKV only: grid.z selects {Q(scale,bf16), K(bf16), V(->VpT)}.
// ---------------------------------------------------------------------------
__global__ __launch_bounds__(256) void gemm128(
    const unsigned short* __restrict__ A0, const unsigned short* __restrict__ A1,
    const unsigned short* __restrict__ A2,
    const unsigned short* __restrict__ W0, const unsigned short* __restrict__ W1,
    const unsigned short* __restrict__ W2,
    const float* __restrict__ b0, const float* __restrict__ b1,
    const float* __restrict__ b2,
    void* __restrict__ C0, void* __restrict__ C1, void* __restrict__ C2,
    int S)
{
    __shared__ __align__(16) unsigned short As[128 * 32];
    __shared__ __align__(16) unsigned short Bs[128 * 32];

    const int z = blockIdx.z;
    const unsigned short* A = (z == 0) ? A0 : (z == 1) ? A1 : A2;
    const unsigned short* W = (z == 0) ? W0 : (z == 1) ? W1 : W2;
    const float* bias       = (z == 0) ? b0 : (z == 1) ? b1 : b2;
    void* C                 = (z == 0) ? C0 : (z == 1) ? C1 : C2;
    const float scale = (z == 0) ? SCALE_Q : 1.0f;
    const int mode = (z == 2) ? 3 : 1;   // 3=VpT, 1=bf16

    const int tid  = threadIdx.x;
    const int wave = tid >> 6;
    const int lane = tid & 63;
    const int quad = lane >> 4;
    const int l16  = lane & 15;
    const int m0 = blockIdx.x * 128;
    const int n0 = blockIdx.y * 128;
    const int wm = (wave & 1) * 64;
    const int wn = (wave >> 1) * 64;
    const int sr = lane >> 2;          // staging row within 16-row group
    const int sc = (lane & 3) << 3;    // staging col chunk (8 shorts = 16 B)

    const floatx4 zero4 = {0.f, 0.f, 0.f, 0.f};
    floatx4 acc[4][4];
    #pragma unroll
    for (int i = 0; i < 4; ++i)
        #pragma unroll
        for (int j = 0; j < 4; ++j) acc[i][j] = zero4;

    for (int k0 = 0; k0 < D_MODEL; k0 += 32) {
        // wave stages A rows [32w,32w+32) and W rows [32w,32w+32), 16/call
        #pragma unroll
        for (int c = 0; c < 2; ++c) {
            const int row = wave * 32 + c * 16;
            gload_lds16(A + (size_t)(m0 + row + sr) * D_MODEL + k0 + sc,
                        As + row * 32);
            gload_lds16(W + (size_t)(n0 + row + sr) * D_MODEL + k0 + sc,
                        Bs + row * 32);
        }
        __syncthreads();

        bf16x8 af[4], bfr[4];
        #pragma unroll
        for (int i = 0; i < 4; ++i)
            af[i] = *(const bf16x8*)(As + (wm + i * 16 + l16) * 32 + quad * 8);
        #pragma unroll
        for (int j = 0; j < 4; ++j)
            bfr[j] = *(const bf16x8*)(Bs + (wn + j * 16 + l16) * 32 + quad * 8);
        #pragma unroll
        for (int i = 0; i < 4; ++i)
            #pragma unroll
            for (int j = 0; j < 4; ++j)
                acc[i][j] = __builtin_amdgcn_mfma_f32_16x16x32_bf16(
                    bfr[j], af[i], acc[i][j], 0, 0, 0);   // swapped: rows=n
        __syncthreads();
    }

    // epilogue: D[i][j] rows (quad*4+r) = n, cols (l16) = m
    #pragma unroll
    for (int i = 0; i < 4; ++i) {
        const int m = m0 + wm + i * 16 + l16;
        #pragma unroll
        for (int j = 0; j < 4; ++j) {
            const int nb = n0 + wn + j * 16 + quad * 4;
            const float4 bv = *(const float4*)(bias + nb);
            float v0 = (acc[i][j][0] + bv.x) * scale;
            float v1 = (acc[i][j][1] + bv.y) * scale;
            float v2 = (acc[i][j][2] + bv.z) * scale;
            float v3 = (acc[i][j][3] + bv.w) * scale;
            if (mode == 1) {
                ushortx4 o = {f2bf(v0), f2bf(v1), f2bf(v2), f2bf(v3)};
                *(ushortx4*)((unsigned short*)C + (size_t)m * D_MODEL + nb) = o;
            } else {
                // VpT[(bb*H + h)*64 + d][s]: 4 consecutive d, fixed s=m
                const int bb = m / S, s = m - bb * S;
                const int hh = nb >> 6, d = nb & 63;
                unsigned short* base = (unsigned short*)C +
                    ((size_t)(bb * N_HEADS + hh) * D_K + d) * S + s;
                base[0]         = f2bf(v0);
                base[(size_t)S]     = f2bf(v1);
                base[(size_t)S * 2] = f2bf(v2);
                base[(size_t)S * 3] = f2bf(v3);
            }
        }
    }
}

// ---------------------------------------------------------------------------
// Final O @ Wo^T + bo -> fp32. 64x128 output tile -> grid (M/64, 6) = 768
// blocks = 3 blocks/CU. Wave owns 64x32, acc[4][2], 8 MFMA/k-iter.
// ---------------------------------------------------------------------------
__global__ __launch_bounds__(256) void gemm64o(
    const unsigned short* __restrict__ A,
    const unsigned short* __restrict__ W,
    const float* __restrict__ bias,
    float* __restrict__ C)
{
    __shared__ __align__(16) unsigned short As[64 * 32];
    __shared__ __align__(16) unsigned short Bs[128 * 32];

    const int tid  = threadIdx.x;
    const int wave = tid >> 6;
    const int lane = tid & 63;
    const int quad = lane >> 4;
    const int l16  = lane & 15;
    const int m0 = blockIdx.x * 64;
    const int n0 = blockIdx.y * 128;
    const int wn = wave * 32;
    const int sr = lane >> 2;          // staging row within 16-row group
    const int sc = (lane & 3) << 3;    // staging col chunk (8 shorts = 16 B)

    const floatx4 zero4 = {0.f, 0.f, 0.f, 0.f};
    floatx4 acc[4][2];
    #pragma unroll
    for (int i = 0; i < 4; ++i)
        #pragma unroll
        for (int j = 0; j < 2; ++j) acc[i][j] = zero4;

    for (int k0 = 0; k0 < D_MODEL; k0 += 32) {
        // staging: waves 0,1 -> As rows [32w,32w+32) + Bs group 96/112;
        //          waves 2,3 -> Bs rows [48(w-2), 48(w-2)+48)
        if (wave < 2) {
            const int g0 = wave * 32;
            gload_lds16(A + (size_t)(m0 + g0 + sr) * D_MODEL + k0 + sc,
                        As + g0 * 32);
            gload_lds16(A + (size_t)(m0 + g0 + 16 + sr) * D_MODEL + k0 + sc,
                        As + (g0 + 16) * 32);
            const int bg = 96 + wave * 16;
            gload_lds16(W + (size_t)(n0 + bg + sr) * D_MODEL + k0 + sc,
                        Bs + bg * 32);
        } else {
            const int bg = (wave - 2) * 48;
            #pragma unroll
            for (int c = 0; c < 3; ++c)
                gload_lds16(W + (size_t)(n0 + bg + c * 16 + sr) * D_MODEL + k0 + sc,
                            Bs + (bg + c * 16) * 32);
        }
        __syncthreads();

        bf16x8 af[4], bfr[2];
        #pragma unroll
        for (int i = 0; i < 4; ++i)
            af[i] = *(const bf16x8*)(As + (i * 16 + l16) * 32 + quad * 8);
        #pragma unroll
        for (int j = 0; j < 2; ++j)
            bfr[j] = *(const bf16x8*)(Bs + (wn + j * 16 + l16) * 32 + quad * 8);
        #pragma unroll
        for (int i = 0; i < 4; ++i)
            #pragma unroll
            for (int j = 0; j < 2; ++j)
                acc[i][j] = __builtin_amdgcn_mfma_f32_16x16x32_bf16(
                    bfr[j], af[i], acc[i][j], 0, 0, 0);   // swapped: rows=n
        __syncthreads();
    }

    // epilogue: D[i][j] rows (quad*4+r) = n, cols (l16) = m
    #pragma unroll
    for (int i = 0; i < 4; ++i) {
        const int m = m0 + i * 16 + l16;
        #pragma unroll
        for (int j = 0; j < 2; ++j) {
            const int nb = n0 + wn + j * 16 + quad * 4;
            const float4 bv = *(const float4*)(bias + nb);
            float4 o = {acc[i][j][0] + bv.x, acc[i][j][1] + bv.y,
                        acc[i][j][2] + bv.z, acc[i][j][3] + bv.w};
            *(float4*)(C + (size_t)m * D_MODEL + nb) = o;
        }
    }
}

// ---------------------------------------------------------------------------
// Causal flash attention. R9: LDS-BW fix via q/key wave-split.
// Diagnosis (R2/R6/R7 invariance + arithmetic): each wave re-read the FULL
// K and V tiles per 128-key iteration (32KB/wave-iter); per CU 12 wave-iters
// x 32KB / 2950cy = 130 B/cy ~= 102% of the 128 B/cy LDS peak -> LDS-read
// bound. Fix: wave w owns q-cols [32*(w&1),+32) x keys [64*(w>>1),+64).
// Each K fragment feeds 2 MFMAs (two Q B-operands in regs), each V fragment
// feeds 2 (two P A-operands): LDS reads halve to 16KB/wave-iter; MFMA count
// unchanged (36/wave-iter, no redundancy). Cross-wave partial O/l summed
// once per sel via conflict-free LDS exchange (waves 2,3 publish into
// Ks/Vts-as-scratch; waves 0,1 add + write O).
// Staging identical to R6 (async global_load_lds, source-pre-swizzled XOR;
// all new read rows have row&7 == l16&7 so the same ^sx applies; V col base
// 64*kh2 keeps bit6 outside the 3-bit XOR field).
// exp2 via raw v_exp_f32 (exp2_hw), epilogue rcp via v_rcp_f32.
// Load-balanced pairs (p, 63-p): 33 iters/block; grid 768 = 3 blocks/CU;
// bh = L%24 XCD affinity.
// ---------------------------------------------------------------------------
__global__ __launch_bounds__(256) void flash_attn(
    const unsigned short* __restrict__ Qp,
    const unsigned short* __restrict__ Kp,
    const unsigned short* __restrict__ VpT,
    const int* __restrict__ mask,
    unsigned short* __restrict__ O,   // bf16 [B*S, D_MODEL]
    int S)
{
    __shared__ __align__(16) unsigned short Ks [128 * 64];   // [key][d]  swz
    __shared__ __align__(16) unsigned short Vts[64 * 128];   // [d][key]  swz
    __shared__ __align__(16) float mskf[128];

    const int L  = blockIdx.x;
    const int bh = L % 24;
    const int p  = L / 24;
    const int h  = bh % 12;
    const int b  = bh / 12;
    const int nqt = S >> 6;
    const int tid  = threadIdx.x;
    const int wave = tid >> 6;
    const int lane = tid & 63;
    const int quad = lane >> 4;
    const int l16  = lane & 15;
    const int sx   = (l16 & 7) << 3;   // read-side swizzle field (shorts)
    const int qh   = wave & 1;         // q-col half: q in [32*qh, 32*qh+32)
    const int kh2  = wave >> 1;        // key half: keys [64*kh2, 64*kh2+64)

    const unsigned short* Kbase = Kp  + (size_t)(b * S) * D_MODEL + h * D_K;
    const unsigned short* Vbase = VpT + (size_t)(b * N_HEADS + h) * D_K * S;
    const int* mbase = mask + b * S;

    // DMA staging source maps (per-lane constants)
    const int kgrow = wave * 32 + (lane >> 3);            // + c*8
    const int kgcol = ((lane & 7) ^ (lane >> 3)) << 3;
    const int vgrow = wave * 16 + (lane >> 4);            // + c*4
    const int vgc_e = ((lane & 15) ^ (lane >> 4)) << 3;        // even c
    const int vgc_o = ((lane & 15) ^ (4 + (lane >> 4))) << 3;  // odd  c

    const floatx4 zero4 = {0.f, 0.f, 0.f, 0.f};
    const short one_bf = (short)0x3F80;  // bf16 1.0
    const bf16x8 ones = {one_bf, one_bf, one_bf, one_bf,
                         one_bf, one_bf, one_bf, one_bf};

    #pragma unroll
    for (int sel = 0; sel < 2; ++sel) {
        const int qt = sel ? (nqt - 1 - p) : p;
        const int q0 = qt * 64;

        // Q fragments for this wave's TWO 16-q groups (B-operand: n=l16)
        bf16x8 qf[2][2];
        #pragma unroll
        for (int qg = 0; qg < 2; ++qg) {
            const size_t rowQ =
                (size_t)(b * S + q0 + qh * 32 + qg * 16 + l16) * D_MODEL + h * D_K;
            qf[qg][0] = *(const bf16x8*)(Qp + rowQ + quad * 8);
            qf[qg][1] = *(const bf16x8*)(Qp + rowQ + 32 + quad * 8);
        }

        floatx4 acc2[2][4];   // [qg][d-tile]; C: col=d(l16), row=q(quad*4+r)
        floatx4 accl[2];
        #pragma unroll
        for (int qg = 0; qg < 2; ++qg) {
            accl[qg] = zero4;
            #pragma unroll
            for (int dt = 0; dt < 4; ++dt) acc2[qg][dt] = zero4;
        }

        const int ni = (qt >> 1) + 1;
        for (int kt = 0; kt < ni; ++kt) {
            const int k0 = kt * 128;
            // stage K [128 keys][64 d] and V^T [64 d][128 keys] via async
            // DMA, source pre-swizzled (cooperative: all waves stage all)
            #pragma unroll
            for (int c = 0; c < 4; ++c) {
                gload_lds16(
                    Kbase + (size_t)(k0 + kgrow + c * 8) * D_MODEL + kgcol,
                    (char*)Ks + (wave * 4 + c) * 1024);
                const int vg = (c & 1) ? vgc_o : vgc_e;
                gload_lds16(
                    Vbase + (size_t)(vgrow + c * 4) * S + k0 + vg,
                    (char*)Vts + (wave * 4 + c) * 1024);
            }
            if (tid < 128)
                mskf[tid] = (mbase[k0 + tid] == 0) ? NEG_INF : 0.f;
            __syncthreads();

            // S^T = K Q^T (this wave's 64-key half x 32 q-cols):
            // rows=keys(quad*4+r), cols=q(l16); K frag reused across 2 qg
            floatx4 s[4][2];
            #pragma unroll
            for (int nt = 0; nt < 4; ++nt) {
                const int krow = kh2 * 64 + nt * 16 + l16;
                const unsigned short* kro = Ks + krow * 64;
                const bf16x8 kf0 = *(const bf16x8*)(kro + ((quad * 8) ^ sx));
                const bf16x8 kf1 = *(const bf16x8*)(kro + ((32 + quad * 8) ^ sx));
                const floatx4 cm =
                    *(const floatx4*)(mskf + kh2 * 64 + nt * 16 + quad * 4);
                #pragma unroll
                for (int qg = 0; qg < 2; ++qg) {
                    floatx4 c = cm;
                    c = __builtin_amdgcn_mfma_f32_16x16x32_bf16(kf0, qf[qg][0], c, 0, 0, 0);
                    c = __builtin_amdgcn_mfma_f32_16x16x32_bf16(kf1, qf[qg][1], c, 0, 0, 0);
                    s[nt][qg] = c;
                }
            }

            // causal mask: only the last k-tile of this q-tile needs it
            if (kt == ni - 1) {
                #pragma unroll
                for (int nt = 0; nt < 4; ++nt) {
                    const int kb = k0 + kh2 * 64 + nt * 16 + quad * 4;
                    #pragma unroll
                    for (int qg = 0; qg < 2; ++qg) {
                        const int qa = q0 + qh * 32 + qg * 16 + l16;
                        #pragma unroll
                        for (int r = 0; r < 4; ++r)
                            if (kb + r > qa) s[nt][qg][r] = NEG_INF;
                    }
                }
            }

            // P = exp2(s) via raw v_exp_f32, truncation-packed to bf16 pairs
            unsigned pk0[4][2], pk1[4][2];
            #pragma unroll
            for (int nt = 0; nt < 4; ++nt)
                #pragma unroll
                for (int qg = 0; qg < 2; ++qg) {
                    const float e0 = exp2_hw(s[nt][qg][0]);
                    const float e1 = exp2_hw(s[nt][qg][1]);
                    const float e2 = exp2_hw(s[nt][qg][2]);
                    const float e3 = exp2_hw(s[nt][qg][3]);
                    pk0[nt][qg] = __builtin_amdgcn_perm(
                        __builtin_bit_cast(unsigned, e1),
                        __builtin_bit_cast(unsigned, e0), 0x07060302u);
                    pk1[nt][qg] = __builtin_amdgcn_perm(
                        __builtin_bit_cast(unsigned, e3),
                        __builtin_bit_cast(unsigned, e2), 0x07060302u);
                }

            // O += P V ; l += P 1  (64 local keys -> 2 kh steps); V frag
            // reused across 2 qg. A-operand in-register via permlane swaps.
            #pragma unroll
            for (int kh = 0; kh < 2; ++kh) {
                bf16x8 pf[2];
                #pragma unroll
                for (int qg = 0; qg < 2; ++qg) {
                    uintx2 a32 = __builtin_amdgcn_permlane32_swap(
                        pk0[2 * kh][qg], pk0[2 * kh + 1][qg], false, false);
                    uintx2 b32 = __builtin_amdgcn_permlane32_swap(
                        pk1[2 * kh][qg], pk1[2 * kh + 1][qg], false, false);
                    uintx2 a16 = __builtin_amdgcn_permlane16_swap(
                        a32[0], a32[1], false, false);
                    uintx2 b16 = __builtin_amdgcn_permlane16_swap(
                        b32[0], b32[1], false, false);
                    const uintx4 pw = {a16[0], b16[0], a16[1], b16[1]};
                    pf[qg] = __builtin_bit_cast(bf16x8, pw);
                }
                #pragma unroll
                for (int dt = 0; dt < 4; ++dt) {
                    const int vcol = kh2 * 64 + ((kh * 32 + quad * 8) ^ sx);
                    const bf16x8 vf =
                        *(const bf16x8*)(Vts + (dt * 16 + l16) * 128 + vcol);
                    #pragma unroll
                    for (int qg = 0; qg < 2; ++qg)
                        acc2[qg][dt] = __builtin_amdgcn_mfma_f32_16x16x32_bf16(
                            pf[qg], vf, acc2[qg][dt], 0, 0, 0);
                }
                #pragma unroll
                for (int qg = 0; qg < 2; ++qg)
                    accl[qg] = __builtin_amdgcn_mfma_f32_16x16x32_bf16(
                        pf[qg], ones, accl[qg], 0, 0, 0);
            }
            __syncthreads();
        }

        // cross-wave partial reduction (once per sel): waves kh2==1 publish
        // acc2/accl into Ks/Vts-as-scratch (conflict-free: lane*16B stride),
        // partner (same qh, kh2==0) adds and writes O.
        float* Kf = (float*)Ks;
        float* Vf = (float*)Vts;
        if (kh2 == 1) {
            #pragma unroll
            for (int qg = 0; qg < 2; ++qg) {
                #pragma unroll
                for (int dt = 0; dt < 4; ++dt)
                    *(floatx4*)(Kf + (qh * 8 + qg * 4 + dt) * 256 + lane * 4) =
                        acc2[qg][dt];
                *(floatx4*)(Vf + (qh * 2 + qg) * 256 + lane * 4) = accl[qg];
            }
        }
        __syncthreads();
        if (kh2 == 0) {
            #pragma unroll
            for (int qg = 0; qg < 2; ++qg) {
                accl[qg] += *(const floatx4*)(Vf + (qh * 2 + qg) * 256 + lane * 4);
                #pragma unroll
                for (int dt = 0; dt < 4; ++dt)
                    acc2[qg][dt] +=
                        *(const floatx4*)(Kf + (qh * 8 + qg * 4 + dt) * 256 + lane * 4);
                #pragma unroll
                for (int r = 0; r < 4; ++r) {
                    const float inv = rcp_hw(accl[qg][r]);
                    const int gq = q0 + qh * 32 + qg * 16 + quad * 4 + r;
                    const size_t base = (size_t)(b * S + gq) * D_MODEL + h * D_K;
                    #pragma unroll
                    for (int dt = 0; dt < 4; ++dt)
                        O[base + dt * 16 + l16] = f2bf(acc2[qg][dt][r] * inv);
                }
            }
        }
        __syncthreads();  // LDS reused by next sel's staging
    }
}

// ---------------------------------------------------------------------------
extern "C" void kernel_launch(void* const* d_in, const int* in_sizes, int n_in,
                              void* d_out, int out_size, void* d_ws, size_t ws_size,
                              hipStream_t stream) {
    const float* query = (const float*)d_in[0];
    const float* key   = (const float*)d_in[1];
    const float* value = (const float*)d_in[2];
    const int*   mask  = (const int*)d_in[3];
    const float* Wq = (const float*)d_in[4];
    const float* bq = (const float*)d_in[5];
    const float* Wk = (const float*)d_in[6];
    const float* bk = (const float*)d_in[7];
    const float* Wv = (const float*)d_in[8];
    const float* bv = (const float*)d_in[9];
    const float* Wo = (const float*)d_in[10];
    const float* bo = (const float*)d_in[11];

    const int B  = 2;
    const int BS = in_sizes[3];
    const int S  = BS / B;
    const int M  = BS;

    unsigned short* Qp  = (unsigned short*)d_ws;
    unsigned short* Kp  = Qp  + (size_t)M * D_MODEL;
    unsigned short* VpT = Kp  + (size_t)M * D_MODEL;
    unsigned short* Obf = VpT + (size_t)M * D_MODEL;  // qa staging, then O
    unsigned short* Wbf = Obf + (size_t)M * D_MODEL;
    unsigned short* Wqb = Wbf;
    unsigned short* Wkb = Wbf + (size_t)W_ELEMS;
    unsigned short* Wvb = Wbf + (size_t)W_ELEMS * 2;
    unsigned short* Wob = Wbf + (size_t)W_ELEMS * 3;
    // d_out (25.2 MB fp32) doubles as scratch for ka/va bf16 until final GEMM
    unsigned short* ka = (unsigned short*)d_out;
    unsigned short* va = ka + (size_t)M * D_MODEL;

    dim3 blk(256);
    convert_w4<<<dim3(W_ELEMS / 1024, 4), blk, 0, stream>>>(Wq, Wk, Wv, Wo, Wbf);
    convert_a3<<<dim3((M * D_MODEL) / 1024, 3), blk, 0, stream>>>(
        query, key, value, Obf, ka, va);

    gemm128<<<dim3(M / 128, D_MODEL / 128, 3), blk, 0, stream>>>(
        Obf, ka, va, Wqb, Wkb, Wvb, bq, bk, bv, Qp, Kp, VpT, S);

    flash_attn<<<768, blk, 0, stream>>>(Qp, Kp, VpT, mask, Obf, S);

    gemm64o<<<dim3(M / 64, D_MODEL / 128), blk, 0, stream>>>(
        Obf, Wob, bo, (float*)d_out);
}